// Round 2
// baseline (538.290 us; speedup 1.0000x reference)
//
#include <hip/hip_runtime.h>
#include <hip/hip_bf16.h>

typedef __attribute__((ext_vector_type(8))) short short8;
typedef __attribute__((ext_vector_type(4))) float f32x4;

#define NN 8192      // nodes == classes
#define FIN 512
#define HD 64
#define LOG2E 1.44269504088896f

// ---------------- zero helper (no hipMemsetAsync under graph capture) ----------------
__global__ void k_zero(int* __restrict__ p, int n) {
    int i = blockIdx.x * blockDim.x + threadIdx.x;
    if (i < n) p[i] = 0;
}

// ---------------- CSR build ----------------
__global__ void k_count(const int* __restrict__ dst, int E, int* __restrict__ cnt) {
    int e = blockIdx.x * blockDim.x + threadIdx.x;
    if (e < E) atomicAdd(&cnt[dst[e]], 1);
}

__global__ __launch_bounds__(1024) void k_scan(const int* __restrict__ cnt,
        int* __restrict__ offs, int* __restrict__ cursor, float* __restrict__ dinv) {
    __shared__ int wsh[16];
    int t = threadIdx.x;
    int lane = t & 63, wv = t >> 6;
    int v[8], loc[8];
    int s = 0;
#pragma unroll
    for (int j = 0; j < 8; ++j) { v[j] = cnt[t*8+j]; loc[j] = s; s += v[j]; }
    int inc = s;
#pragma unroll
    for (int d = 1; d < 64; d <<= 1) {
        int up = __shfl_up(inc, d, 64);
        if (lane >= d) inc += up;
    }
    if (lane == 63) wsh[wv] = inc;
    __syncthreads();
    if (t < 16) {
        int mv = wsh[t];
        int winc = mv;
#pragma unroll
        for (int d = 1; d < 16; d <<= 1) {
            int up = __shfl_up(winc, d, 16);
            if (t >= d) winc += up;
        }
        wsh[t] = winc - mv;   // exclusive wave base
    }
    __syncthreads();
    int base = wsh[wv] + (inc - s);
#pragma unroll
    for (int j = 0; j < 8; ++j) {
        int o = base + loc[j];
        offs[t*8+j]   = o;
        cursor[t*8+j] = o;
        dinv[t*8+j]   = rsqrtf((float)(v[j] + 1));  // +1 self loop, deg>=1 always
    }
    if (t == 1023) offs[NN] = base + s;
}

__global__ void k_scatter(const int* __restrict__ src, const int* __restrict__ dst, int E,
        int* __restrict__ cursor, int* __restrict__ ssrc) {
    int e = blockIdx.x * blockDim.x + threadIdx.x;
    if (e < E) {
        int pos = atomicAdd(&cursor[dst[e]], 1);
        ssrc[pos] = src[e];
    }
}

// ---------------- layer-1 GEMM: xws = (x @ W1) * dinv[row]  ----------------
// block: 256 thr, 16 rows x 64 cols; K tiled by 128 through LDS.
__global__ __launch_bounds__(256) void k_gemm1(const float* __restrict__ x,
        const float* __restrict__ W1, const float* __restrict__ dinv,
        float* __restrict__ xws) {
    __shared__ float Xs[16][132];
    int t = threadIdx.x;
    int c  = t & 63;
    int rg = t >> 6;             // wave id -> 4-row group
    int br = blockIdx.x * 16;
    float acc[4] = {0.f, 0.f, 0.f, 0.f};
    for (int k0 = 0; k0 < FIN; k0 += 128) {
        __syncthreads();
        int row_ld = t >> 4, kcol = (t & 15) * 8;
        const float* xp = x + (br + row_ld) * FIN + k0 + kcol;
        float4 v0 = *(const float4*)xp;
        float4 v1 = *(const float4*)(xp + 4);
        *(float4*)&Xs[row_ld][kcol]     = v0;
        *(float4*)&Xs[row_ld][kcol + 4] = v1;
        __syncthreads();
#pragma unroll 8
        for (int kk = 0; kk < 128; ++kk) {
            float w = W1[(k0 + kk) * HD + c];
#pragma unroll
            for (int r = 0; r < 4; ++r)
                acc[r] += Xs[rg*4 + r][kk] * w;   // LDS broadcast (wave-uniform addr)
        }
    }
#pragma unroll
    for (int r = 0; r < 4; ++r) {
        int row = br + rg*4 + r;
        xws[row * HD + c] = acc[r] * dinv[row];
    }
}

// ---------------- aggregation: one wave per node, lane = feature ----------------
__global__ __launch_bounds__(256) void k_agg1(const float* __restrict__ xws,
        const int* __restrict__ offs, const int* __restrict__ ssrc,
        const float* __restrict__ dinv, const float* __restrict__ b1,
        float* __restrict__ hs) {
    int lane = threadIdx.x & 63;
    int node = (blockIdx.x << 2) + (threadIdx.x >> 6);
    float acc = xws[node * HD + lane];             // self-loop term (already *dinv[self])
    int beg = offs[node], end = offs[node + 1];
    for (int base = beg; base < end; base += 64) {
        int rem = end - base;
        int n = rem < 64 ? rem : 64;
        int idx = (lane < n) ? ssrc[base + lane] : 0;
        for (int j = 0; j < n; ++j) {
            int s = __shfl(idx, j, 64);
            acc += xws[s * HD + lane];
        }
    }
    float dv = dinv[node];
    float h = fmaxf(acc * dv + b1[lane], 0.f);     // agg + bias, relu
    hs[node * HD + lane] = h * dv;                 // pre-scale for layer-2 messages
}

__global__ __launch_bounds__(256) void k_agg2(const float* __restrict__ hs,
        const int* __restrict__ offs, const int* __restrict__ ssrc,
        const float* __restrict__ dinv, __hip_bfloat16* __restrict__ gbf) {
    int lane = threadIdx.x & 63;
    int node = (blockIdx.x << 2) + (threadIdx.x >> 6);
    float acc = hs[node * HD + lane];
    int beg = offs[node], end = offs[node + 1];
    for (int base = beg; base < end; base += 64) {
        int rem = end - base;
        int n = rem < 64 ? rem : 64;
        int idx = (lane < n) ? ssrc[base + lane] : 0;
        for (int j = 0; j < n; ++j) {
            int s = __shfl(idx, j, 64);
            acc += hs[s * HD + lane];
        }
    }
    gbf[node * HD + lane] = __float2bfloat16(acc * dinv[node]);
}

// ---------------- pack W2 (fp32 [64][8192]) -> bf16 MFMA B-fragment order ----------------
// W2p[((c16*2 + kc)*64 + lane)*8 + j] = W2[kc*32 + (lane>>4)*8 + j][c16*16 + (lane&15)]
__global__ void k_packw2(const float* __restrict__ W2, __hip_bfloat16* __restrict__ w2p) {
    int i = blockIdx.x * blockDim.x + threadIdx.x;   // 0 .. 64*8192-1
    int k  = i >> 13;
    int cc = i & 8191;
    int c16 = cc >> 4, cl = cc & 15;
    int kc = k >> 5, q = (k >> 3) & 3, j = k & 7;
    int dsti = ((c16 * 2 + kc) * 64 + q * 16 + cl) * 8 + j;
    w2p[dsti] = __float2bfloat16(W2[i]);
}

// ---------------- fused GEMM2 (bf16 MFMA) + log_softmax ----------------
// block: 512 thr (8 waves), 32 rows; each wave owns 64 c16 col-tiles of 16 cols.
// Pass1: sum exp(logit) per row (no max-shift needed: |logit| << 88).
// Pass2: recompute MFMAs, write logit - ln(sum).
__global__ __launch_bounds__(512) void k_fused(
        const __hip_bfloat16* __restrict__ gbf,
        const __hip_bfloat16* __restrict__ w2p,
        const float* __restrict__ b2,
        float* __restrict__ out) {
    __shared__ float red[32][8];
    __shared__ float Lsh[32];
    const unsigned short* g  = (const unsigned short*)gbf;
    const unsigned short* wp = (const unsigned short*)w2p;
    int t = threadIdx.x;
    int lane = t & 63, wv = t >> 6;
    int m = lane & 15, q = lane >> 4;
    int row0 = blockIdx.x * 32;

    // A fragments (loop-invariant): A[m=lane&15][k = kc*32 + q*8 + j]
    short8 a[2][2];
#pragma unroll
    for (int rt = 0; rt < 2; ++rt)
#pragma unroll
        for (int kc = 0; kc < 2; ++kc)
            a[rt][kc] = *(const short8*)(g + (row0 + rt*16 + m) * HD + kc*32 + q*8);

    float sm0[4] = {0.f,0.f,0.f,0.f};
    float sm1[4] = {0.f,0.f,0.f,0.f};
    for (int it = 0; it < 64; ++it) {
        int c16 = wv * 64 + it;
        const unsigned short* bp = wp + c16 * 1024;
        short8 b0  = *(const short8*)(bp + lane * 8);
        short8 b1v = *(const short8*)(bp + 512 + lane * 8);
        float bias = b2[c16 * 16 + m];
        f32x4 d0 = {0.f,0.f,0.f,0.f};
        f32x4 d1 = {0.f,0.f,0.f,0.f};
        d0 = __builtin_amdgcn_mfma_f32_16x16x32_bf16(a[0][0], b0,  d0, 0, 0, 0);
        d0 = __builtin_amdgcn_mfma_f32_16x16x32_bf16(a[0][1], b1v, d0, 0, 0, 0);
        d1 = __builtin_amdgcn_mfma_f32_16x16x32_bf16(a[1][0], b0,  d1, 0, 0, 0);
        d1 = __builtin_amdgcn_mfma_f32_16x16x32_bf16(a[1][1], b1v, d1, 0, 0, 0);
#pragma unroll
        for (int r = 0; r < 4; ++r) {
            sm0[r] += exp2f((d0[r] + bias) * LOG2E);
            sm1[r] += exp2f((d1[r] + bias) * LOG2E);
        }
    }
    // reduce sums across the 16 lanes sharing a row (same q, varying lane&15)
#pragma unroll
    for (int r = 0; r < 4; ++r) {
#pragma unroll
        for (int msk = 1; msk < 16; msk <<= 1) {
            sm0[r] += __shfl_xor(sm0[r], msk, 64);
            sm1[r] += __shfl_xor(sm1[r], msk, 64);
        }
    }
    if (m == 0) {
#pragma unroll
        for (int r = 0; r < 4; ++r) {
            red[q*4 + r][wv]      = sm0[r];
            red[16 + q*4 + r][wv] = sm1[r];
        }
    }
    __syncthreads();
    if (t < 32) {
        float s = 0.f;
#pragma unroll
        for (int j = 0; j < 8; ++j) s += red[t][j];
        Lsh[t] = logf(s);
    }
    __syncthreads();
    float L0[4], L1[4];
#pragma unroll
    for (int r = 0; r < 4; ++r) {
        L0[r] = Lsh[q*4 + r];
        L1[r] = Lsh[16 + q*4 + r];
    }
    // pass 2: recompute + write (nontemporal: keep W2p/g hot in L2)
    for (int it = 0; it < 64; ++it) {
        int c16 = wv * 64 + it;
        const unsigned short* bp = wp + c16 * 1024;
        short8 b0  = *(const short8*)(bp + lane * 8);
        short8 b1v = *(const short8*)(bp + 512 + lane * 8);
        float bias = b2[c16 * 16 + m];
        f32x4 d0 = {0.f,0.f,0.f,0.f};
        f32x4 d1 = {0.f,0.f,0.f,0.f};
        d0 = __builtin_amdgcn_mfma_f32_16x16x32_bf16(a[0][0], b0,  d0, 0, 0, 0);
        d0 = __builtin_amdgcn_mfma_f32_16x16x32_bf16(a[0][1], b1v, d0, 0, 0, 0);
        d1 = __builtin_amdgcn_mfma_f32_16x16x32_bf16(a[1][0], b0,  d1, 0, 0, 0);
        d1 = __builtin_amdgcn_mfma_f32_16x16x32_bf16(a[1][1], b1v, d1, 0, 0, 0);
        int col = c16 * 16 + m;
#pragma unroll
        for (int r = 0; r < 4; ++r) {
            __builtin_nontemporal_store(d0[r] + bias - L0[r],
                                        out + (row0 + q*4 + r) * NN + col);
            __builtin_nontemporal_store(d1[r] + bias - L1[r],
                                        out + (row0 + 16 + q*4 + r) * NN + col);
        }
    }
}

extern "C" void kernel_launch(void* const* d_in, const int* in_sizes, int n_in,
                              void* d_out, int out_size, void* d_ws, size_t ws_size,
                              hipStream_t stream) {
    const float* x  = (const float*)d_in[0];
    const int*   ei = (const int*)d_in[1];     // int32 on device (JAX x64 disabled)
    const float* W1 = (const float*)d_in[2];
    const float* b1 = (const float*)d_in[3];
    const float* W2 = (const float*)d_in[4];
    const float* b2 = (const float*)d_in[5];
    float* out = (float*)d_out;
    int E = in_sizes[1] / 2;
    const int* esrc = ei;
    const int* edst = ei + E;

    // Small tables + buffers that must survive into k_fused live in d_ws (~2.2 MB).
    // offs gets a full 36 KB slot: it needs NN+1 = 8193 ints (round-1 crash was
    // offs[8192] aliasing cursor[0]).
    char* w = (char*)d_ws;
    int*   cnt    = (int*)(w);                            // 32 KB
    int*   offs   = (int*)(w + (32 << 10));               // 36 KB slot (8193 used)
    int*   cursor = (int*)(w + (68 << 10));               // 32 KB
    float* dinv   = (float*)(w + (100 << 10));            // 32 KB
    __hip_bfloat16* gbf = (__hip_bfloat16*)(w + (192 << 10));              // 1 MB
    __hip_bfloat16* w2p = (__hip_bfloat16*)(w + (192 << 10) + (1 << 20));  // 1 MB

    // Large intermediates that are DEAD before k_fused runs live in the tail of
    // d_out (256 MB, fully overwritten by k_fused): ssrc/xws/hs = ~6 MB.
    size_t total = (size_t)NN * NN;
    float* hs   = out + total - (size_t)NN * HD;          // 2 MB
    float* xws  = hs  - (size_t)NN * HD;                  // 2 MB
    int*   ssrc = (int*)xws - E;                          // 2 MB

    int eb = (E + 255) / 256;
    k_zero   <<<(NN + 255) / 256, 256, 0, stream>>>(cnt, NN);
    k_count  <<<eb, 256, 0, stream>>>(edst, E, cnt);
    k_scan   <<<1, 1024, 0, stream>>>(cnt, offs, cursor, dinv);
    k_scatter<<<eb, 256, 0, stream>>>(esrc, edst, E, cursor, ssrc);
    k_gemm1  <<<NN / 16, 256, 0, stream>>>(x, W1, dinv, xws);
    k_agg1   <<<NN / 4, 256, 0, stream>>>(xws, offs, ssrc, dinv, b1, hs);
    k_agg2   <<<NN / 4, 256, 0, stream>>>(hs, offs, ssrc, dinv, gbf);
    k_packw2 <<<(HD * NN) / 256, 256, 0, stream>>>(W2, w2p);
    k_fused  <<<NN / 32, 512, 0, stream>>>(gbf, w2p, b2, out);
}

// Round 3
// 451.705 us; speedup vs baseline: 1.1917x; 1.1917x over previous
//
#include <hip/hip_runtime.h>
#include <hip/hip_bf16.h>

typedef __attribute__((ext_vector_type(8))) short short8;
typedef __attribute__((ext_vector_type(16))) float f32x16;

#define NN 8192      // nodes == classes
#define FIN 512
#define HD 64
#define LOG2E 1.44269504088896f

#if __has_builtin(__builtin_amdgcn_exp2f)
#define EXP2(x) __builtin_amdgcn_exp2f(x)
#else
#define EXP2(x) exp2f(x)
#endif

// ---------------- pack W2 -> 32x32x16 MFMA B-fragment order, + zero cnt ----------------
// B frag for (c32, kc): lane holds col = lane&31, k = kc*16 + (lane>>5)*8 + j
// w2p short index: ((c32*4 + kc)*64 + (k>>3 &1)*32 + col)*8 + (k&7)
__global__ void k_pack_zero(const float* __restrict__ W2, __hip_bfloat16* __restrict__ w2p,
                            int* __restrict__ cnt) {
    int i = blockIdx.x * blockDim.x + threadIdx.x;   // 0 .. 64*8192-1
    if (i < NN) cnt[i] = 0;
    int k  = i >> 13;            // 0..63
    int cc = i & 8191;
    int c32 = cc >> 5, cl = cc & 31;
    int kc = k >> 4, hh = (k >> 3) & 1, j = k & 7;
    int dsti = ((c32 * 4 + kc) * 64 + hh * 32 + cl) * 8 + j;
    w2p[dsti] = __float2bfloat16(W2[i]);
}

// ---------------- CSR build ----------------
__global__ void k_count(const int* __restrict__ dst, int E, int* __restrict__ cnt) {
    int e = blockIdx.x * blockDim.x + threadIdx.x;
    if (e < E) atomicAdd(&cnt[dst[e]], 1);
}

__global__ __launch_bounds__(1024) void k_scan(const int* __restrict__ cnt,
        int* __restrict__ offs, int* __restrict__ cursor, float* __restrict__ dinv) {
    __shared__ int wsh[16];
    int t = threadIdx.x;
    int lane = t & 63, wv = t >> 6;
    int v[8], loc[8];
    int s = 0;
#pragma unroll
    for (int j = 0; j < 8; ++j) { v[j] = cnt[t*8+j]; loc[j] = s; s += v[j]; }
    int inc = s;
#pragma unroll
    for (int d = 1; d < 64; d <<= 1) {
        int up = __shfl_up(inc, d, 64);
        if (lane >= d) inc += up;
    }
    if (lane == 63) wsh[wv] = inc;
    __syncthreads();
    if (t < 16) {
        int mv = wsh[t];
        int winc = mv;
#pragma unroll
        for (int d = 1; d < 16; d <<= 1) {
            int up = __shfl_up(winc, d, 16);
            if (t >= d) winc += up;
        }
        wsh[t] = winc - mv;   // exclusive wave base
    }
    __syncthreads();
    int base = wsh[wv] + (inc - s);
#pragma unroll
    for (int j = 0; j < 8; ++j) {
        int o = base + loc[j];
        offs[t*8+j]   = o;
        cursor[t*8+j] = o;
        dinv[t*8+j]   = rsqrtf((float)(v[j] + 1));  // +1 self loop
    }
    if (t == 1023) offs[NN] = base + s;
}

__global__ void k_scatter(const int* __restrict__ src, const int* __restrict__ dst, int E,
        int* __restrict__ cursor, int* __restrict__ ssrc) {
    int e = blockIdx.x * blockDim.x + threadIdx.x;
    if (e < E) {
        int pos = atomicAdd(&cursor[dst[e]], 1);
        ssrc[pos] = src[e];
    }
}

// ---------------- layer-1 GEMM: xws = (x @ W1) * dinv[row]  ----------------
__global__ __launch_bounds__(256) void k_gemm1(const float* __restrict__ x,
        const float* __restrict__ W1, const float* __restrict__ dinv,
        float* __restrict__ xws) {
    __shared__ float Xs[16][132];
    int t = threadIdx.x;
    int c  = t & 63;
    int rg = t >> 6;
    int br = blockIdx.x * 16;
    float acc[4] = {0.f, 0.f, 0.f, 0.f};
    for (int k0 = 0; k0 < FIN; k0 += 128) {
        __syncthreads();
        int row_ld = t >> 4, kcol = (t & 15) * 8;
        const float* xp = x + (br + row_ld) * FIN + k0 + kcol;
        float4 v0 = *(const float4*)xp;
        float4 v1 = *(const float4*)(xp + 4);
        *(float4*)&Xs[row_ld][kcol]     = v0;
        *(float4*)&Xs[row_ld][kcol + 4] = v1;
        __syncthreads();
#pragma unroll 8
        for (int kk = 0; kk < 128; ++kk) {
            float w = W1[(k0 + kk) * HD + c];
#pragma unroll
            for (int r = 0; r < 4; ++r)
                acc[r] += Xs[rg*4 + r][kk] * w;
        }
    }
#pragma unroll
    for (int r = 0; r < 4; ++r) {
        int row = br + rg*4 + r;
        xws[row * HD + c] = acc[r] * dinv[row];
    }
}

// ---------------- aggregation: one wave per node, lane = feature, 8-deep MLP ----------------
__global__ __launch_bounds__(256) void k_agg1(const float* __restrict__ xws,
        const int* __restrict__ offs, const int* __restrict__ ssrc,
        const float* __restrict__ dinv, const float* __restrict__ b1,
        float* __restrict__ hs) {
    int lane = threadIdx.x & 63;
    int node = (blockIdx.x << 2) + (threadIdx.x >> 6);
    const float* xp = xws + lane;
    float acc = xp[node * HD];
    int beg = offs[node], end = offs[node + 1];
    for (int base = beg; base < end; base += 64) {
        int rem = end - base;
        int n = rem < 64 ? rem : 64;
        int idx = (lane < n) ? ssrc[base + lane] : 0;
        int j = 0;
        for (; j + 8 <= n; j += 8) {
            int s0 = __shfl(idx, j+0, 64), s1 = __shfl(idx, j+1, 64);
            int s2 = __shfl(idx, j+2, 64), s3 = __shfl(idx, j+3, 64);
            int s4 = __shfl(idx, j+4, 64), s5 = __shfl(idx, j+5, 64);
            int s6 = __shfl(idx, j+6, 64), s7 = __shfl(idx, j+7, 64);
            float v0 = xp[s0*HD], v1 = xp[s1*HD], v2 = xp[s2*HD], v3 = xp[s3*HD];
            float v4 = xp[s4*HD], v5 = xp[s5*HD], v6 = xp[s6*HD], v7 = xp[s7*HD];
            acc += ((v0+v1)+(v2+v3)) + ((v4+v5)+(v6+v7));
        }
        for (; j < n; ++j) {
            int s = __shfl(idx, j, 64);
            acc += xp[s*HD];
        }
    }
    float dv = dinv[node];
    float h = fmaxf(acc * dv + b1[lane], 0.f);
    hs[node * HD + lane] = h * dv;                 // pre-scale for layer-2 messages
}

__global__ __launch_bounds__(256) void k_agg2(const float* __restrict__ hs,
        const int* __restrict__ offs, const int* __restrict__ ssrc,
        const float* __restrict__ dinv, __hip_bfloat16* __restrict__ gbf) {
    int lane = threadIdx.x & 63;
    int node = (blockIdx.x << 2) + (threadIdx.x >> 6);
    const float* hp = hs + lane;
    float acc = hp[node * HD];
    int beg = offs[node], end = offs[node + 1];
    for (int base = beg; base < end; base += 64) {
        int rem = end - base;
        int n = rem < 64 ? rem : 64;
        int idx = (lane < n) ? ssrc[base + lane] : 0;
        int j = 0;
        for (; j + 8 <= n; j += 8) {
            int s0 = __shfl(idx, j+0, 64), s1 = __shfl(idx, j+1, 64);
            int s2 = __shfl(idx, j+2, 64), s3 = __shfl(idx, j+3, 64);
            int s4 = __shfl(idx, j+4, 64), s5 = __shfl(idx, j+5, 64);
            int s6 = __shfl(idx, j+6, 64), s7 = __shfl(idx, j+7, 64);
            float v0 = hp[s0*HD], v1 = hp[s1*HD], v2 = hp[s2*HD], v3 = hp[s3*HD];
            float v4 = hp[s4*HD], v5 = hp[s5*HD], v6 = hp[s6*HD], v7 = hp[s7*HD];
            acc += ((v0+v1)+(v2+v3)) + ((v4+v5)+(v6+v7));
        }
        for (; j < n; ++j) {
            int s = __shfl(idx, j, 64);
            acc += hp[s*HD];
        }
    }
    gbf[node * HD + lane] = __float2bfloat16(acc * dinv[node]);
}

// ---------------- fused GEMM2 (32x32x16 bf16 MFMA) + log_softmax ----------------
// block: 512 thr (8 waves), 32 rows; wave wv covers c32 tiles wv*32..wv*32+31.
// C/D layout: col = lane&31, row = (r&3) + 8*(r>>2) + 4*(lane>>5)  [m74/m101]
// Stores: each reg r -> 2 x 128-B full aligned lines (32 lanes x 4B).
__global__ __launch_bounds__(512) void k_fused(
        const __hip_bfloat16* __restrict__ gbf,
        const __hip_bfloat16* __restrict__ w2p,
        const float* __restrict__ b2,
        float* __restrict__ out) {
    __shared__ float red[32][8];
    __shared__ float Lsh[32];
    const unsigned short* g  = (const unsigned short*)gbf;
    const unsigned short* wp = (const unsigned short*)w2p;
    int t = threadIdx.x;
    int lane = t & 63, wv = t >> 6;
    int cl = lane & 31, hh = lane >> 5;
    int row0 = blockIdx.x * 32;

    // A fragments (loop-invariant): A[row=lane&31][k = kc*16 + (lane>>5)*8 + j]
    short8 a[4];
#pragma unroll
    for (int kc = 0; kc < 4; ++kc)
        a[kc] = *(const short8*)(g + (row0 + cl) * HD + kc*16 + hh*8);

    float sm[16];
#pragma unroll
    for (int r = 0; r < 16; ++r) sm[r] = 0.f;

    for (int it = 0; it < 32; ++it) {
        int c32 = wv * 32 + it;
        const unsigned short* bp = wp + c32 * 2048 + lane * 8;
        float bias = b2[c32 * 32 + cl];
        f32x16 d;
#pragma unroll
        for (int r = 0; r < 16; ++r) d[r] = 0.f;
#pragma unroll
        for (int kc = 0; kc < 4; ++kc) {
            short8 b = *(const short8*)(bp + kc * 512);
            d = __builtin_amdgcn_mfma_f32_32x32x16_bf16(a[kc], b, d, 0, 0, 0);
        }
#pragma unroll
        for (int r = 0; r < 16; ++r)
            sm[r] += EXP2((d[r] + bias) * LOG2E);
    }
    // reduce across the 32 lanes sharing each row (cols)
#pragma unroll
    for (int r = 0; r < 16; ++r) {
#pragma unroll
        for (int msk = 1; msk < 32; msk <<= 1)
            sm[r] += __shfl_xor(sm[r], msk, 64);
    }
    if (cl == 0) {
#pragma unroll
        for (int r = 0; r < 16; ++r)
            red[(r & 3) + 8 * (r >> 2) + 4 * hh][wv] = sm[r];
    }
    __syncthreads();
    if (t < 32) {
        float s = 0.f;
#pragma unroll
        for (int j = 0; j < 8; ++j) s += red[t][j];
        Lsh[t] = logf(s);
    }
    __syncthreads();
    float L[16];
#pragma unroll
    for (int r = 0; r < 16; ++r)
        L[r] = Lsh[(r & 3) + 8 * (r >> 2) + 4 * hh];

    // pass 2: recompute + coalesced nt stores
    for (int it = 0; it < 32; ++it) {
        int c32 = wv * 32 + it;
        const unsigned short* bp = wp + c32 * 2048 + lane * 8;
        float bias = b2[c32 * 32 + cl];
        f32x16 d;
#pragma unroll
        for (int r = 0; r < 16; ++r) d[r] = 0.f;
#pragma unroll
        for (int kc = 0; kc < 4; ++kc) {
            short8 b = *(const short8*)(bp + kc * 512);
            d = __builtin_amdgcn_mfma_f32_32x32x16_bf16(a[kc], b, d, 0, 0, 0);
        }
        float* op = out + (size_t)row0 * NN + c32 * 32 + cl;
#pragma unroll
        for (int r = 0; r < 16; ++r) {
            int rp = (r & 3) + 8 * (r >> 2) + 4 * hh;
            __builtin_nontemporal_store(d[r] + bias - L[r], op + (size_t)rp * NN);
        }
    }
}

extern "C" void kernel_launch(void* const* d_in, const int* in_sizes, int n_in,
                              void* d_out, int out_size, void* d_ws, size_t ws_size,
                              hipStream_t stream) {
    const float* x  = (const float*)d_in[0];
    const int*   ei = (const int*)d_in[1];
    const float* W1 = (const float*)d_in[2];
    const float* b1 = (const float*)d_in[3];
    const float* W2 = (const float*)d_in[4];
    const float* b2 = (const float*)d_in[5];
    float* out = (float*)d_out;
    int E = in_sizes[1] / 2;
    const int* esrc = ei;
    const int* edst = ei + E;

    // d_ws layout (~2.2 MB): small tables + buffers read by k_fused.
    char* w = (char*)d_ws;
    int*   cnt    = (int*)(w);                            // 32 KB
    int*   offs   = (int*)(w + (32 << 10));               // 36 KB slot (8193 ints)
    int*   cursor = (int*)(w + (68 << 10));               // 32 KB
    float* dinv   = (float*)(w + (100 << 10));            // 32 KB
    __hip_bfloat16* gbf = (__hip_bfloat16*)(w + (192 << 10));              // 1 MB
    __hip_bfloat16* w2p = (__hip_bfloat16*)(w + (192 << 10) + (1 << 20));  // 1 MB

    // Dead-before-k_fused intermediates live in the tail of d_out (overwritten after).
    size_t total = (size_t)NN * NN;
    float* hs   = out + total - (size_t)NN * HD;          // 2 MB
    float* xws  = hs  - (size_t)NN * HD;                  // 2 MB
    int*   ssrc = (int*)xws - E;                          // 2 MB

    int eb = (E + 255) / 256;
    k_pack_zero<<<(HD * NN) / 256, 256, 0, stream>>>(W2, w2p, cnt);
    k_count  <<<eb, 256, 0, stream>>>(edst, E, cnt);
    k_scan   <<<1, 1024, 0, stream>>>(cnt, offs, cursor, dinv);
    k_scatter<<<eb, 256, 0, stream>>>(esrc, edst, E, cursor, ssrc);
    k_gemm1  <<<NN / 16, 256, 0, stream>>>(x, W1, dinv, xws);
    k_agg1   <<<NN / 4, 256, 0, stream>>>(xws, offs, ssrc, dinv, b1, hs);
    k_agg2   <<<NN / 4, 256, 0, stream>>>(hs, offs, ssrc, dinv, gbf);
    k_fused  <<<NN / 32, 512, 0, stream>>>(gbf, w2p, b2, out);
}